// Round 1
// 1158.466 us; speedup vs baseline: 1.2762x; 1.2762x over previous
//
#include <hip/hip_runtime.h>
#include <cstdint>
#include <cstddef>

#define M_DIM 8192
#define N_DIM 11008
#define K_DIM 4096

// row-offset constants (elements) for half-tile staging
#define AH1 524288   // 128 * K_DIM
#define RO1 262144   // 64 * K_DIM

typedef __attribute__((ext_vector_type(8))) short short8;
typedef __attribute__((ext_vector_type(4))) float floatx4;
typedef __attribute__((ext_vector_type(8))) unsigned short ushort8;

// RNE fp32 -> bf16 (no NaN handling needed: inputs are finite normals)
__device__ __forceinline__ unsigned short f2bf(float f) {
    unsigned int u = __float_as_uint(f);
    unsigned int r = (u + 0x7fffu + ((u >> 16) & 1u)) >> 16;
    return (unsigned short)r;
}

__device__ __forceinline__ void gl_lds16(const unsigned short* g, unsigned short* l) {
    __builtin_amdgcn_global_load_lds(
        (const __attribute__((address_space(1))) void*)g,
        (__attribute__((address_space(3))) void*)l,
        16, 0, 0);
}

// ---------------- prepass: fp32 -> bf16 ----------------
__global__ __launch_bounds__(256) void cvt_f32_bf16(const float* __restrict__ in,
                                                    unsigned short* __restrict__ out) {
    size_t i = ((size_t)blockIdx.x * 256 + threadIdx.x) * 8;
    float4 v0 = *(const float4*)(in + i);
    float4 v1 = *(const float4*)(in + i + 4);
    ushort8 o;
    o[0] = f2bf(v0.x); o[1] = f2bf(v0.y); o[2] = f2bf(v0.z); o[3] = f2bf(v0.w);
    o[4] = f2bf(v1.x); o[5] = f2bf(v1.y); o[6] = f2bf(v1.z); o[7] = f2bf(v1.w);
    *(ushort8*)(out + i) = o;
}

// ---------------- prepass: int32 (values in [-128,127]) -> bf16 (exact) ----------------
__global__ __launch_bounds__(256) void cvt_i32_bf16(const int* __restrict__ in,
                                                    unsigned short* __restrict__ out) {
    size_t i = ((size_t)blockIdx.x * 256 + threadIdx.x) * 8;
    int4 v0 = *(const int4*)(in + i);
    int4 v1 = *(const int4*)(in + i + 4);
    ushort8 o;
    o[0] = f2bf((float)v0.x); o[1] = f2bf((float)v0.y);
    o[2] = f2bf((float)v0.z); o[3] = f2bf((float)v0.w);
    o[4] = f2bf((float)v1.x); o[5] = f2bf((float)v1.y);
    o[6] = f2bf((float)v1.z); o[7] = f2bf((float)v1.w);
    *(ushort8*)(out + i) = o;
}

// =====================================================================
// 256x256-tile, BK=64, 8-wave, 8-phase counted-vmcnt GEMM (m201-style).
//
// A: [M][K] bf16 row-major, W: [N][K] bf16 row-major (B^T layout).
// out[m][n] = (sum_k A[m][k]*W[n][k]) * scale[n] + bias[n]
//
// LDS: 2 buffers x 4 half-tiles {A-h0, B-h0, A-h1, B-h1}, each 128x64 bf16
// (16 KiB) = 128 KiB total. Slot swizzle: 16B slot s of row r holds global
// k-slot (s ^ (r&7)) -- applied on the gload_lds *source* address (dest
// stays linear, rule #21) and on the ds_read address (involution).
//
// Waves: 8 = 2(wm) x 4(wn). Wave output 128x64, STRIDED quadrants:
// rows {wm*64 + qm*128 + 0..63}, cols {wn*32 + qn*128 + 0..31}. This makes
// phase r=1 consume exactly A-h(0), r=2 B-h(0), r=3 A-h(1), r=0 B-h(1),
// so each half is overwritable one phase after its read and stages can run
// 3 half-tiles ahead under s_waitcnt vmcnt(6) (never 0 in the main loop).
//
// Per phase: {ds_read half -> regs; stage 1 half-tile (2x gload_lds); BAR;
// setprio(1); 16 MFMA (one C-quadrant, K=64); setprio(0); lgkmcnt(0)
// [write-after-read seal]; [vmcnt(6) on r=0]; BAR}.
// =====================================================================

#define SBAR  __builtin_amdgcn_s_barrier()
#define LGKM0 asm volatile("s_waitcnt lgkmcnt(0)" ::: "memory")
#define VM6   asm volatile("s_waitcnt vmcnt(6)" ::: "memory")
#define VM0   asm volatile("s_waitcnt vmcnt(0)" ::: "memory")
#define PRIO1 __builtin_amdgcn_s_setprio(1)
#define PRIO0 __builtin_amdgcn_s_setprio(0)

// stage half-tile j (0=A-h0,1=B-h0,2=A-h1,3=B-h1) of K-tile T; p=pA|pB, h=j>>1
#define STAGE(T, j, p, h) do {                                              \
    unsigned short* _d = &lds[(((T) & 1) << 15) + ((j) << 13) + stlds];     \
    const unsigned short* _s = (p) + ((size_t)(T) << 6) + (size_t)((h) * AH1); \
    gl_lds16(_s, _d);                                                       \
    gl_lds16(_s + RO1, _d + 4096);                                          \
} while (0)

#define LDA(qm, T) do {                                                     \
    const unsigned short* _b = &lds[(((T) & 1) << 15) + ((qm) << 14)];      \
    _Pragma("unroll")                                                       \
    for (int mi = 0; mi < 4; ++mi) {                                        \
        aR[qm][mi][0] = *(const short8*)(_b + aoff0 + mi * 1024);           \
        aR[qm][mi][1] = *(const short8*)(_b + aoff1 + mi * 1024);           \
    }                                                                       \
} while (0)

#define LDB(qn, T) do {                                                     \
    const unsigned short* _b = &lds[(((T) & 1) << 15) + ((qn) << 14) + 8192]; \
    _Pragma("unroll")                                                       \
    for (int nj = 0; nj < 2; ++nj) {                                        \
        bR[qn][nj][0] = *(const short8*)(_b + boff0 + nj * 1024);           \
        bR[qn][nj][1] = *(const short8*)(_b + boff1 + nj * 1024);           \
    }                                                                       \
} while (0)

#define QUAD(qm, qn) do {                                                   \
    _Pragma("unroll")                                                       \
    for (int mi = 0; mi < 4; ++mi)                                          \
        _Pragma("unroll")                                                   \
        for (int nj = 0; nj < 2; ++nj) {                                    \
            acc[qm][qn][mi][nj] = __builtin_amdgcn_mfma_f32_16x16x32_bf16(  \
                aR[qm][mi][0], bR[qn][nj][0], acc[qm][qn][mi][nj], 0, 0, 0); \
            acc[qm][qn][mi][nj] = __builtin_amdgcn_mfma_f32_16x16x32_bf16(  \
                aR[qm][mi][1], bR[qn][nj][1], acc[qm][qn][mi][nj], 0, 0, 0); \
        }                                                                   \
} while (0)

__global__ __launch_bounds__(512, 2) void gemm_bf16_256(
    const unsigned short* __restrict__ A,
    const unsigned short* __restrict__ W,
    const float* __restrict__ scale,
    const float* __restrict__ bias,
    float* __restrict__ out)
{
    __shared__ __align__(16) unsigned short lds[65536];   // 128 KiB

    const int tid  = threadIdx.x;
    const int wave = tid >> 6;
    const int lane = tid & 63;
    const int wm   = wave >> 2;     // 0..1
    const int wn   = wave & 3;      // 0..3

    // T1: XCD-aware tile mapping. 1376 blocks = 8 XCDs x 172. Each XCD gets a
    // 4-row mt band x all 43 nt (bijective: 172 = 4*43).
    const int orig = blockIdx.x;
    const int xcd  = orig & 7;
    const int lin  = orig >> 3;            // 0..171
    const int mt   = xcd * 4 + (lin & 3);  // 0..31
    const int nt   = lin >> 2;             // 0..42

    // ---- ds_read addressing (element offsets within a 128x64 half region) ----
    const int frow = lane & 15;
    const int s0   = lane >> 4;
    const int swz  = frow & 7;
    const int aoff0 = (wm * 64 + frow) * 64 + (((0 + s0) ^ swz) << 3);
    const int aoff1 = (wm * 64 + frow) * 64 + (((4 + s0) ^ swz) << 3);
    const int boff0 = (wn * 32 + frow) * 64 + (((0 + s0) ^ swz) << 3);
    const int boff1 = (wn * 32 + frow) * 64 + (((4 + s0) ^ swz) << 3);

    // ---- staging addressing ----
    // thread t covers region row (t>>3) [+64 on round 1], 16B slot (t&7);
    // source k pre-swizzled so linear LDS dest + swizzled read agree.
    const int stlds = wave << 9;           // wave-uniform LDS base (elems)
    const int trow  = tid >> 3;            // 0..63
    const int ksw   = ((tid & 7) ^ (trow & 7)) << 3;
    const unsigned short* pA = A + (size_t)(mt * 256 + trow) * K_DIM + ksw;
    const unsigned short* pB = W + (size_t)(nt * 256 + trow) * K_DIM + ksw;

    short8  aR[2][4][2];
    short8  bR[2][2][2];
    floatx4 acc[2][2][4][2];
#pragma unroll
    for (int qm = 0; qm < 2; ++qm)
#pragma unroll
        for (int qn = 0; qn < 2; ++qn)
#pragma unroll
            for (int mi = 0; mi < 4; ++mi)
#pragma unroll
                for (int nj = 0; nj < 2; ++nj)
                    acc[qm][qn][mi][nj] = (floatx4){0.f, 0.f, 0.f, 0.f};

    // ---- prologue: stage tile0 (4 halves) + tile1 (3 halves); tile0 guaranteed ----
    STAGE(0, 0, pA, 0); STAGE(0, 1, pB, 0); STAGE(0, 2, pA, 1); STAGE(0, 3, pB, 1);
    STAGE(1, 0, pA, 0); STAGE(1, 1, pB, 0); STAGE(1, 2, pA, 1);
    VM6;                                   // 14 issued, <=6 outstanding => tile0 done
    SBAR;

    // ---- t = 0 (peeled: no trailing quadrant yet) ----
    LDA(0, 0); STAGE(1, 3, pB, 1); SBAR;
    LGKM0; SBAR;
    LDB(0, 0); STAGE(2, 0, pA, 0); SBAR;
    PRIO1; QUAD(0, 0); PRIO0; LGKM0; SBAR;
    LDA(1, 0); STAGE(2, 1, pB, 0); SBAR;
    PRIO1; QUAD(1, 0); PRIO0; LGKM0; SBAR;
    LDB(1, 0); STAGE(2, 2, pA, 1); SBAR;
    PRIO1; QUAD(0, 1); PRIO0; LGKM0; VM6; SBAR;

    // ---- steady state: tiles 1..61 ----
    for (int t = 1; t <= 61; ++t) {
        // r=1: read A-h0(t); stage B-h1(t+1); compute (1,1) of t-1
        LDA(0, t); STAGE(t + 1, 3, pB, 1); SBAR;
        PRIO1; QUAD(1, 1); PRIO0; LGKM0; SBAR;
        // r=2: read B-h0(t); stage A-h0(t+2); compute (0,0) of t
        LDB(0, t); STAGE(t + 2, 0, pA, 0); SBAR;
        PRIO1; QUAD(0, 0); PRIO0; LGKM0; SBAR;
        // r=3: read A-h1(t); stage B-h0(t+2); compute (1,0) of t
        LDA(1, t); STAGE(t + 2, 1, pB, 0); SBAR;
        PRIO1; QUAD(1, 0); PRIO0; LGKM0; SBAR;
        // r=0: read B-h1(t); stage A-h1(t+2); compute (0,1) of t
        LDB(1, t); STAGE(t + 2, 2, pA, 1); SBAR;
        PRIO1; QUAD(0, 1); PRIO0; LGKM0; VM6; SBAR;
    }

    // ---- drain: last stage, then tiles 62 and 63 with no more writers ----
    STAGE(63, 3, pB, 1);
    VM0; SBAR;
    PRIO1; QUAD(1, 1); PRIO0;              // (1,1) of tile 61

    LDA(0, 62); LDB(0, 62);
    PRIO1; QUAD(0, 0); PRIO0;
    LDA(1, 62);
    PRIO1; QUAD(1, 0); PRIO0;
    LDB(1, 62);
    PRIO1; QUAD(0, 1); QUAD(1, 1); PRIO0;

    LDA(0, 63); LDB(0, 63);
    PRIO1; QUAD(0, 0); PRIO0;
    LDA(1, 63);
    PRIO1; QUAD(1, 0); PRIO0;
    LDB(1, 63);
    PRIO1; QUAD(0, 1); QUAD(1, 1); PRIO0;

    // ---- epilogue: C/D layout col=lane&15, row=(lane>>4)*4+reg [m89-verified] ----
    const int r0 = s0 << 2;
#pragma unroll
    for (int qn = 0; qn < 2; ++qn)
#pragma unroll
        for (int nj = 0; nj < 2; ++nj) {
            const int col = nt * 256 + qn * 128 + wn * 32 + nj * 16 + frow;
            const float sc = scale[col];
            const float bz = bias[col];
#pragma unroll
            for (int qm = 0; qm < 2; ++qm)
#pragma unroll
                for (int mi = 0; mi < 4; ++mi) {
                    const int row = mt * 256 + qm * 128 + wm * 64 + mi * 16 + r0;
                    size_t base = (size_t)row * N_DIM + col;
                    floatx4 v = acc[qm][qn][mi][nj];
                    out[base]             = v[0] * sc + bz;
                    out[base + N_DIM]     = v[1] * sc + bz;
                    out[base + 2 * N_DIM] = v[2] * sc + bz;
                    out[base + 3 * N_DIM] = v[3] * sc + bz;
                }
        }
}

// ---------------- correctness fallback if workspace is too small ----------------
__global__ __launch_bounds__(256) void naive_kernel(
    const float* __restrict__ A,
    const int* __restrict__ W,
    const float* __restrict__ scale,
    const float* __restrict__ bias,
    float* __restrict__ out)
{
    const int n = blockIdx.x * 256 + threadIdx.x;
    const int m = blockIdx.y;
    const float* a = A + (size_t)m * K_DIM;
    const int* w = W + (size_t)n * K_DIM;
    float acc = 0.f;
    for (int k = 0; k < K_DIM; ++k) acc += a[k] * (float)w[k];
    out[(size_t)m * N_DIM + n] = acc * scale[n] + bias[n];
}

extern "C" void kernel_launch(void* const* d_in, const int* in_sizes, int n_in,
                              void* d_out, int out_size, void* d_ws, size_t ws_size,
                              hipStream_t stream) {
    const float* input  = (const float*)d_in[0];   // [4,2048,4096] fp32
    const int*   weight = (const int*)d_in[1];     // [11008,4096] int (values -128..127)
    const float* scale  = (const float*)d_in[2];   // [11008]
    const float* bias   = (const float*)d_in[3];   // [1,11008]
    float* out = (float*)d_out;

    const size_t nA = (size_t)M_DIM * K_DIM;       // 33,554,432
    const size_t nW = (size_t)N_DIM * K_DIM;       // 45,088,768
    const size_t need = nA * 2 + nW * 2;           // 157.3 MB bf16 workspace

    if (ws_size >= need) {
        unsigned short* wsA = (unsigned short*)d_ws;
        unsigned short* wsW = wsA + nA;
        cvt_f32_bf16<<<dim3((unsigned)(nA / (256 * 8))), 256, 0, stream>>>(input, wsA);
        cvt_i32_bf16<<<dim3((unsigned)(nW / (256 * 8))), 256, 0, stream>>>(weight, wsW);
        gemm_bf16_256<<<dim3((N_DIM / 256) * (M_DIM / 256)), 512, 0, stream>>>(wsA, wsW, scale, bias, out);
    } else {
        naive_kernel<<<dim3(N_DIM / 256, M_DIM), 256, 0, stream>>>(input, weight, scale, bias, out);
    }
}